// Round 13
// baseline (229.773 us; speedup 1.0000x reference)
//
#include <hip/hip_runtime.h>
#include <hip/hip_bf16.h>
#include <cstdint>
#include <cstddef>

using bf16 = __hip_bfloat16;
using short8 = __attribute__((ext_vector_type(8))) short;
using f32x4  = __attribute__((ext_vector_type(4))) float;

constexpr int Bc = 8;
constexpr int Tc = 4097;
constexpr int Dc = 512;         // model dim
constexpr int Hc = 8;
constexpr int Mrows = Bc * Tc;  // 32776
constexpr int Mpad2 = 33024;    // padded rows
constexpr int NW = 64;          // windows per (b,h)

__device__ __forceinline__ float bf2f(unsigned short u) {
    union { unsigned int i; float f; } v;
    v.i = ((unsigned int)u) << 16;
    return v.f;
}

__device__ __forceinline__ unsigned short f2b(float f) {
    union { float f; unsigned int i; } u; u.f = f;
    unsigned int r = u.i + 0x7FFFu + ((u.i >> 16) & 1u);  // RNE
    return (unsigned short)(r >> 16);
}

__device__ __forceinline__ void gload_lds16(const void* g, void* l) {
    __builtin_amdgcn_global_load_lds(
        (const __attribute__((address_space(1))) void*)g,
        (__attribute__((address_space(3))) void*)l, 16, 0, 0);
}

// ---------------------------------------------------------------------------
// Convert x (fp32 [Mrows][512]) -> bf16 [Mpad2][512]; pad rows zeroed.
// ---------------------------------------------------------------------------
__global__ __launch_bounds__(256)
void k_cvt_x(const float* __restrict__ x, bf16* __restrict__ xb)
{
    size_t i8 = ((size_t)blockIdx.x * 256 + threadIdx.x) * 8;
    if (i8 >= (size_t)Mpad2 * 512) return;
    union { short s[8]; short8 v; } o;
    if (i8 < (size_t)Mrows * 512) {
        float4 v0 = *(const float4*)(x + i8);
        float4 v1 = *(const float4*)(x + i8 + 4);
        o.s[0] = (short)f2b(v0.x); o.s[1] = (short)f2b(v0.y);
        o.s[2] = (short)f2b(v0.z); o.s[3] = (short)f2b(v0.w);
        o.s[4] = (short)f2b(v1.x); o.s[5] = (short)f2b(v1.y);
        o.s[6] = (short)f2b(v1.z); o.s[7] = (short)f2b(v1.w);
    } else {
        o.v = short8{0,0,0,0,0,0,0,0};
    }
    *(short8*)((short*)xb + i8) = o.v;
}

// ---------------------------------------------------------------------------
// Convert + transpose weight: w fp32 [K][N] -> wT bf16 [N][K].
// ---------------------------------------------------------------------------
__global__ __launch_bounds__(256)
void k_cvt_wT(const float* __restrict__ w, bf16* __restrict__ wT, int K, int N)
{
    __shared__ float t[32][33];
    int bn = blockIdx.x * 32, bk = blockIdx.y * 32;
    int tx = threadIdx.x & 31, ty = threadIdx.x >> 5;  // 32 x 8
    #pragma unroll
    for (int j = 0; j < 4; ++j)
        t[ty + j * 8][tx] = w[(size_t)(bk + ty + j * 8) * N + bn + tx];
    __syncthreads();
    #pragma unroll
    for (int j = 0; j < 4; ++j)
        wT[(size_t)(bn + ty + j * 8) * K + bk + tx] =
            __float2bfloat16(t[tx][ty + j * 8]);
}

// ---------------------------------------------------------------------------
// B-DIRECT MFMA GEMM: 128x128 tile, BK=64, 4 waves. A staged in LDS (dbuf,
// 32 KiB, r6-verified rotation swizzle); B fragments loaded DIRECTLY from
// global (L2-hot 1.5MB panel) into parity-double-buffered registers.
// Rationale: all prior variants were LDS-read-bound (~128 b128/CU/step vs
// ~310cy MFMA); removing B from LDS halves that floor and decouples B from
// the barrier chain.
// vmcnt ledger (issue order per step: B(t+1):8 plain loads, then A(t+2):4
// gload_lds): wait vmcnt(12) = A(t+1) landed; tail vmcnt(8) at t==6.
// Compiler auto-inserts its own (exact) waits for the B register uses.
// ---------------------------------------------------------------------------
template <int NT>
__global__ __launch_bounds__(256)
void k_gemm_bd(const bf16* __restrict__ A, const bf16* __restrict__ Bt,
               bf16* __restrict__ C, int Mlim)
{
    constexpr int N = NT * 128;
    __shared__ short lds[16384];   // 2 bufs x A(128x64) = 32 KiB

    const int tid = threadIdx.x;
    const int lane = tid & 63, wave = tid >> 6;
    const int lo = lane & 15, g = lane >> 4;
    const int wr = wave >> 1, wc = wave & 1;

    // bijective XCD swizzle (m204), m-tile-major linear id
    const int nwg = 257 * NT;
    const int orig = blockIdx.x;
    const int qq = nwg >> 3, rr = nwg & 7;
    const int xc = orig & 7, o8 = orig >> 3;
    const int swz = (xc < rr ? xc * (qq + 1) : rr * (qq + 1) + (xc - rr) * qq) + o8;
    const int bm = (swz / NT) * 128, bn = (swz % NT) * 128;

    // ---- A staging: 128 rows x 8 chunks(16B) = 1024 chunks / 256 thr = 4
    const bf16* aSrc[4];
    int dstOff[4];
    #pragma unroll
    for (int i = 0; i < 4; ++i) {
        int d = i * 256 + tid;
        int row = d >> 3, c = d & 7;
        int ck = (c - row) & 7;                 // rotated source chunk
        aSrc[i] = A + (size_t)(bm + row) * 512 + ck * 8;
        dstOff[i] = d * 8;
    }

    auto STAGE = [&](int kt) {
        const int bb = (kt & 1) * 8192;
        #pragma unroll
        for (int i = 0; i < 4; ++i)
            gload_lds16(aSrc[i] + kt * 64, lds + bb + dstOff[i]);
    };

    // ---- B direct addresses: frag (ni,ks) at row bn+wc*64+ni*16+lo,
    //      k = kt*64 + ks*32 + g*8  (16B per lane; full 128B line per (row,kt))
    const bf16* bPtr[4];
    #pragma unroll
    for (int ni = 0; ni < 4; ++ni)
        bPtr[ni] = Bt + (size_t)(bn + wc * 64 + ni * 16 + lo) * 512 + g * 8;

    // ---- A fragment read constants (rotation inverse) ----
    const int colk[2] = { (g + (lo & 7)) & 7, (g + 4 + (lo & 7)) & 7 };
    const int arow0 = wr * 64 + lo;

    f32x4 acc[4][4] = {};
    short8 b0[4][2], b1[4][2];   // parity-selected B buffers (static idx only)

    // ---- prologue: A(0), A(1) staged; B(0) into b0 ----
    STAGE(0);
    STAGE(1);
    asm volatile("" ::: "memory");   // pin B loads after A stages (ledger order)
    #pragma unroll
    for (int ni = 0; ni < 4; ++ni) {
        b0[ni][0] = *(const short8*)(bPtr[ni]);
        b0[ni][1] = *(const short8*)(bPtr[ni] + 32);
    }
    asm volatile("s_waitcnt vmcnt(12)" ::: "memory");  // A(0) landed
    asm volatile("s_barrier" ::: "memory");

    // ---- one step; t compile-time; bc = B(t), bnx receives B(t+1) ----
    auto STEP = [&](int t, short8 (&bc)[4][2], short8 (&bnx)[4][2]) {
        // issue B(t+1) (before the asm barrier => ledger position fixed)
        if (t < 7) {
            #pragma unroll
            for (int ni = 0; ni < 4; ++ni) {
                bnx[ni][0] = *(const short8*)(bPtr[ni] + (t + 1) * 64);
                bnx[ni][1] = *(const short8*)(bPtr[ni] + (t + 1) * 64 + 32);
            }
        }
        const short* bufA = lds + (t & 1) * 8192;
        #pragma unroll
        for (int ks = 0; ks < 2; ++ks) {
            short8 af[4];
            #pragma unroll
            for (int mi = 0; mi < 4; ++mi)
                af[mi] = *(const short8*)(bufA + (arow0 + mi * 16) * 64 + colk[ks] * 8);
            __builtin_amdgcn_s_setprio(1);
            #pragma unroll
            for (int mi = 0; mi < 4; ++mi)
                #pragma unroll
                for (int ni = 0; ni < 4; ++ni)
                    acc[mi][ni] = __builtin_amdgcn_mfma_f32_16x16x32_bf16(
                        bc[ni][ks], af[mi], acc[mi][ni], 0, 0, 0);
            __builtin_amdgcn_s_setprio(0);
        }
        asm volatile("s_waitcnt lgkmcnt(0)" ::: "memory");
        asm volatile("s_barrier" ::: "memory");
        if (t < 6) {
            STAGE(t + 2);                                 // into buf[t&1]
            asm volatile("s_waitcnt vmcnt(12)" ::: "memory"); // A(t+1) landed
            asm volatile("s_barrier" ::: "memory");
        } else if (t == 6) {
            asm volatile("s_waitcnt vmcnt(8)" ::: "memory");  // A(7) landed
            asm volatile("s_barrier" ::: "memory");
        }
    };

    #pragma unroll
    for (int tt = 0; tt < 4; ++tt) {
        STEP(2 * tt,     b0, b1);
        STEP(2 * tt + 1, b1, b0);
    }

    // ---- epilogue: m = lane&15 dim, n = (lane>>4)*4 + r (vector stores) ----
    #pragma unroll
    for (int mi = 0; mi < 4; ++mi) {
        int m = bm + wr * 64 + mi * 16 + lo;
        if (m < Mlim) {
            #pragma unroll
            for (int ni = 0; ni < 4; ++ni) {
                int n = bn + wc * 64 + ni * 16 + g * 4;
                ushort4 o = { f2b(acc[mi][ni][0]), f2b(acc[mi][ni][1]),
                              f2b(acc[mi][ni][2]), f2b(acc[mi][ni][3]) };
                *(ushort4*)(C + (size_t)m * N + n) = o;
            }
        }
    }
}

// ---------------------------------------------------------------------------
// 128x128-tile, BK=64, 4-wave dbuf MFMA GEMM (r6 structure, verbatim).
// Used for the out-projection (bf16 A, fp32 out) — near memory floor.
// ---------------------------------------------------------------------------
template <typename OutT, int NT>
__global__ __launch_bounds__(256)
void k_gemm_dbuf(const bf16* __restrict__ A, const bf16* __restrict__ Bt,
                 OutT* __restrict__ C, int Mlim)
{
    constexpr int N = NT * 128;
    __shared__ short lds[32768];

    const int tid = threadIdx.x;
    const int lane = tid & 63, wave = tid >> 6;
    const int lo = lane & 15, g = lane >> 4;
    const int wr = wave >> 1, wc = wave & 1;

    const int nwg = 257 * NT;
    const int orig = blockIdx.x;
    const int qq = nwg >> 3, rr = nwg & 7;
    const int xc = orig & 7, o8 = orig >> 3;
    const int swz = (xc < rr ? xc * (qq + 1) : rr * (qq + 1) + (xc - rr) * qq) + o8;
    const int bm = (swz / NT) * 128, bn = (swz % NT) * 128;

    const bf16* aSrc[4]; const bf16* bSrc[4];
    int dstOff[4];
    #pragma unroll
    for (int i = 0; i < 4; ++i) {
        int d = i * 256 + tid;
        int row = d >> 3, c = d & 7;
        int ck = (c - row) & 7;
        aSrc[i] = A  + (size_t)(bm + row) * 512 + ck * 8;
        bSrc[i] = Bt + (size_t)(bn + row) * 512 + ck * 8;
        dstOff[i] = d * 8;
    }

    auto STAGE = [&](int kt) {
        const int bb = (kt & 1) * 16384;
        #pragma unroll
        for (int i = 0; i < 4; ++i)
            gload_lds16(aSrc[i] + kt * 64, lds + bb + dstOff[i]);
        #pragma unroll
        for (int i = 0; i < 4; ++i)
            gload_lds16(bSrc[i] + kt * 64, lds + bb + 8192 + dstOff[i]);
    };

    const int colk[2] = { (g + (lo & 7)) & 7, (g + 4 + (lo & 7)) & 7 };
    const int arow0 = wr * 64 + lo;
    const int brow0 = wc * 64 + lo;

    f32x4 acc[4][4] = {};

    STAGE(0);
    STAGE(1);
    asm volatile("s_waitcnt vmcnt(8)" ::: "memory");
    __builtin_amdgcn_s_barrier();

    for (int t = 0; t < 8; ++t) {
        const short* bufA = lds + (t & 1) * 16384;
        const short* bufB = bufA + 8192;

        #pragma unroll
        for (int ks = 0; ks < 2; ++ks) {
            const int col = colk[ks];
            short8 af[4], bfr[4];
            #pragma unroll
            for (int mi = 0; mi < 4; ++mi)
                af[mi] = *(const short8*)(bufA + (arow0 + mi * 16) * 64 + col * 8);
            #pragma unroll
            for (int ni = 0; ni < 4; ++ni)
                bfr[ni] = *(const short8*)(bufB + (brow0 + ni * 16) * 64 + col * 8);
            __builtin_amdgcn_s_setprio(1);
            #pragma unroll
            for (int mi = 0; mi < 4; ++mi)
                #pragma unroll
                for (int ni = 0; ni < 4; ++ni)
                    acc[mi][ni] = __builtin_amdgcn_mfma_f32_16x16x32_bf16(
                        bfr[ni], af[mi], acc[mi][ni], 0, 0, 0);
            __builtin_amdgcn_s_setprio(0);
        }

        asm volatile("s_waitcnt lgkmcnt(0)" ::: "memory");
        __builtin_amdgcn_s_barrier();
        if (t < 6) {
            STAGE(t + 2);
            asm volatile("s_waitcnt vmcnt(8)" ::: "memory");
            __builtin_amdgcn_s_barrier();
        } else if (t == 6) {
            asm volatile("s_waitcnt vmcnt(0)" ::: "memory");
            __builtin_amdgcn_s_barrier();
        }
    }

    #pragma unroll
    for (int mi = 0; mi < 4; ++mi) {
        int m = bm + wr * 64 + mi * 16 + lo;
        if (m < Mlim) {
            #pragma unroll
            for (int ni = 0; ni < 4; ++ni) {
                int n = bn + wc * 64 + ni * 16 + g * 4;
                if constexpr (sizeof(OutT) == 2) {
                    ushort4 o = { f2b(acc[mi][ni][0]), f2b(acc[mi][ni][1]),
                                  f2b(acc[mi][ni][2]), f2b(acc[mi][ni][3]) };
                    *(ushort4*)((bf16*)C + (size_t)m * N + n) = o;
                } else {
                    float4 o = { acc[mi][ni][0], acc[mi][ni][1],
                                 acc[mi][ni][2], acc[mi][ni][3] };
                    *(float4*)((float*)C + (size_t)m * N + n) = o;
                }
            }
        }
    }
}

// ---------------------------------------------------------------------------
// Window attention (tokens 1..4096), MFMA, with fused token-0 partials.
// (r9 version, unchanged)
// ---------------------------------------------------------------------------
__global__ __launch_bounds__(256)
void k_attn_win(const bf16* __restrict__ qkv, bf16* __restrict__ aout,
                float* __restrict__ part)
{
    __shared__ __attribute__((aligned(16))) unsigned short pS[64 * 64];
    __shared__ __attribute__((aligned(16))) unsigned short vT[64 * 64];
    __shared__ float q0s[64];
    __shared__ float pTok[64];
    __shared__ float oPart[4][64];

    const int n = blockIdx.x, h = blockIdx.y, b = blockIdx.z;
    const int tid = threadIdx.x;
    const int wave = tid >> 6, lane = tid & 63;
    const int lo = lane & 15, g = lane >> 4;

    const bf16* base = qkv + ((size_t)b * Tc + 1 + (size_t)n * 64) * 1536 + h * 64;
    const bf16* kbase = base + 512;
    const bf16* vbase = base + 1024;

    {
        const int key = tid & 63;
        const int d0 = (tid >> 6) * 16;
        const bf16* vp = vbase + (size_t)key * 1536 + d0;
        ushort4 u[4];
        #pragma unroll
        for (int q = 0; q < 4; ++q) u[q] = *(const ushort4*)(vp + q * 4);
        const unsigned short vals[16] = {
            u[0].x, u[0].y, u[0].z, u[0].w, u[1].x, u[1].y, u[1].z, u[1].w,
            u[2].x, u[2].y, u[2].z, u[2].w, u[3].x, u[3].y, u[3].z, u[3].w };
        #pragma unroll
        for (int j = 0; j < 16; ++j) {
            int d = d0 + j;
            int byteoff = d * 128 + ((key * 2) ^ ((d & 7) << 4));
            *(unsigned short*)((char*)vT + byteoff) = vals[j];
        }
    }

    if (tid < 64)
        q0s[tid] = bf2f(*(const unsigned short*)
            (qkv + (size_t)b * Tc * 1536 + h * 64 + tid));

    short8 qf[2];
    {
        const bf16* qp = base + (size_t)(wave * 16 + lo) * 1536 + g * 8;
        qf[0] = *(const short8*)(qp);
        qf[1] = *(const short8*)(qp + 32);
    }

    f32x4 sacc[4] = {};
    #pragma unroll
    for (int ni = 0; ni < 4; ++ni) {
        const bf16* kp = kbase + (size_t)(ni * 16 + lo) * 1536 + g * 8;
        short8 k0 = *(const short8*)(kp);
        short8 k1 = *(const short8*)(kp + 32);
        sacc[ni] = __builtin_amdgcn_mfma_f32_16x16x32_bf16(qf[0], k0, sacc[ni], 0, 0, 0);
        sacc[ni] = __builtin_amdgcn_mfma_f32_16x16x32_bf16(qf[1], k1, sacc[ni], 0, 0, 0);
    }

    __syncthreads();  // barrier 1: vT + q0s ready

    float m_w = 0.f, s_w = 0.f;
    if (wave == 0) {
        const bf16* kp = kbase + (size_t)lane * 1536;
        float l = 0.f;
        #pragma unroll
        for (int d8 = 0; d8 < 8; ++d8) {
            short8 kv = *(const short8*)(kp + d8 * 8);
            #pragma unroll
            for (int e = 0; e < 8; ++e)
                l = fmaf(q0s[d8 * 8 + e], bf2f((unsigned short)kv[e]), l);
        }
        l *= 0.125f;
        float mm = l;
        #pragma unroll
        for (int off = 1; off < 64; off <<= 1) mm = fmaxf(mm, __shfl_xor(mm, off));
        float p = __expf(l - mm);
        float ss = p;
        #pragma unroll
        for (int off = 1; off < 64; off <<= 1) ss += __shfl_xor(ss, off);
        pTok[lane] = p;
        m_w = mm; s_w = ss;
    }

    float pv[4][4];
    float inv[4];
    #pragma unroll
    for (int r = 0; r < 4; ++r) {
        float m = fmaxf(fmaxf(sacc[0][r], sacc[1][r]),
                        fmaxf(sacc[2][r], sacc[3][r])) * 0.125f;
        m = fmaxf(m, __shfl_xor(m, 1));
        m = fmaxf(m, __shfl_xor(m, 2));
        m = fmaxf(m, __shfl_xor(m, 4));
        m = fmaxf(m, __shfl_xor(m, 8));
        float s = 0.f;
        #pragma unroll
        for (int ni = 0; ni < 4; ++ni) {
            float e = __expf(sacc[ni][r] * 0.125f - m);
            pv[ni][r] = e;
            s += e;
        }
        s += __shfl_xor(s, 1);
        s += __shfl_xor(s, 2);
        s += __shfl_xor(s, 4);
        s += __shfl_xor(s, 8);
        inv[r] = 1.f / s;
    }

    #pragma unroll
    for (int ni = 0; ni < 4; ++ni) {
        #pragma unroll
        for (int r = 0; r < 4; ++r) {
            int qrow = wave * 16 + g * 4 + r;
            int col = ni * 16 + lo;
            int byteoff = qrow * 128 + ((col * 2) ^ ((qrow & 7) << 4));
            *(unsigned short*)((char*)pS + byteoff) = f2b(pv[ni][r]);
        }
    }
    __syncthreads();  // barrier 2: pS + pTok ready

    f32x4 oacc[4] = {};
    #pragma unroll
    for (int s = 0; s < 2; ++s) {
        int arow2 = wave * 16 + lo;
        int abyte = arow2 * 128 + (((s * 32 + g * 8) * 2) ^ ((arow2 & 7) << 4));
        short8 pa = *(const short8*)((const char*)pS + abyte);
        #pragma unroll
        for (int nd = 0; nd < 4; ++nd) {
            int d = nd * 16 + lo;
            int bbyte = d * 128 + (((s * 32 + g * 8) * 2) ^ ((d & 7) << 4));
            short8 vb = *(const short8*)((const char*)vT + bbyte);
            oacc[nd] = __builtin_amdgcn_mfma_f32_16x16x32_bf16(pa, vb, oacc[nd], 0, 0, 0);
        }
    }

    {
        const int d = tid & 63, qq = tid >> 6;
        float po = 0.f;
        #pragma unroll
        for (int j16 = 0; j16 < 16; ++j16) {
            int j = qq * 16 + j16;
            int byteoff = d * 128 + ((j * 2) ^ ((d & 7) << 4));
            po = fmaf(pTok[j],
                      bf2f(*(const unsigned short*)((const char*)vT + byteoff)),
                      po);
        }
        oPart[qq][d] = po;
    }

    #pragma unroll
    for (int nd = 0; nd < 4; ++nd) {
        #pragma unroll
        for (int r = 0; r < 4; ++r) {
            int t = 1 + n * 64 + wave * 16 + g * 4 + r;
            aout[((size_t)b * Tc + t) * Dc + h * 64 + nd * 16 + lo] =
                __float2bfloat16(oacc[nd][r] * inv[r]);
        }
    }

    __syncthreads();  // barrier 3: oPart ready

    if (tid < 64) {
        float o0 = oPart[0][tid] + oPart[1][tid] + oPart[2][tid] + oPart[3][tid];
        float* pout = part + ((size_t)(b * Hc + h) * NW + n) * 66;
        pout[tid] = o0;
        if (tid == 0) { pout[64] = m_w; pout[65] = s_w; }
    }
}

// ---------------------------------------------------------------------------
// Token-0 reduce (r9 version, unchanged).
// ---------------------------------------------------------------------------
__global__ __launch_bounds__(64)
void k_tok0_reduce(const float* __restrict__ part, const bf16* __restrict__ qkv,
                   bf16* __restrict__ aout)
{
    const int h = blockIdx.x, b = blockIdx.y;
    const int lane = threadIdx.x;
    const float* basep = part + (size_t)(b * Hc + h) * NW * 66;
    const bf16* qrow = qkv + (size_t)b * Tc * 1536 + h * 64;

    float l0 = bf2f(*(const unsigned short*)(qrow + lane)) *
               bf2f(*(const unsigned short*)(qrow + 512 + lane));
    #pragma unroll
    for (int off = 1; off < 64; off <<= 1) l0 += __shfl_xor(l0, off);
    l0 *= 0.125f;

    float M = basep[lane * 66 + 64];
    #pragma unroll
    for (int off = 1; off < 64; off <<= 1) M = fmaxf(M, __shfl_xor(M, off));
    M = fmaxf(M, l0);

    float S = 0.f, o = 0.f;
    for (int c = 0; c < NW; ++c) {
        const float* pp = basep + c * 66;
        float w = __expf(pp[64] - M);
        S += pp[65] * w;
        o = fmaf(pp[lane], w, o);
    }
    float p0 = __expf(l0 - M);
    S += p0;
    o = fmaf(p0, bf2f(*(const unsigned short*)(qrow + 1024 + lane)), o);

    aout[(size_t)b * Tc * Dc + h * 64 + lane] = __float2bfloat16(o / S);
}

// ---------------------------------------------------------------------------
extern "C" void kernel_launch(void* const* d_in, const int* in_sizes, int n_in,
                              void* d_out, int out_size, void* d_ws, size_t ws_size,
                              hipStream_t stream)
{
    const float* x     = (const float*)d_in[0];
    const float* w_qkv = (const float*)d_in[1];
    const float* w_out = (const float*)d_in[2];
    float* out = (float*)d_out;

    // ws layout (bf16 elems): qkv [Mrows*1536] | xa [Mpad2*512] (xb & aout
    // share; rows >= Mrows stay zero from cvt_x pad) | wqT [1536*512] |
    // woT [512*512]. token-0 partials reuse wqT (dead after QKV GEMM).
    bf16* qkv = (bf16*)d_ws;
    bf16* xa  = qkv + (size_t)Mrows * 1536;
    bf16* wqT = xa  + (size_t)Mpad2 * 512;
    bf16* woT = wqT + (size_t)1536 * 512;
    float* part = (float*)wqT;

    // 1) conversions
    {
        int nblk = (int)(((size_t)Mpad2 * 512 / 8 + 255) / 256);
        k_cvt_x<<<nblk, 256, 0, stream>>>(x, xa);
    }
    k_cvt_wT<<<dim3(48, 16), 256, 0, stream>>>(w_qkv, wqT, 512, 1536);
    k_cvt_wT<<<dim3(16, 16), 256, 0, stream>>>(w_out, woT, 512, 512);

    // 2) qkv = x @ w_qkv  (B-direct: A in LDS dbuf, B from L2 into regs)
    k_gemm_bd<12><<<257 * 12, 256, 0, stream>>>(xa, wqT, qkv, Mrows);

    // 3) attention: MFMA windows with fused token-0 partials, then reduce
    k_attn_win<<<dim3(64, Hc, Bc), 256, 0, stream>>>(qkv, xa, part);
    k_tok0_reduce<<<dim3(Hc, Bc), dim3(64), 0, stream>>>(part, qkv, xa);

    // 4) out = attn_out @ w_out  (r6 dbuf — near memory floor)
    k_gemm_dbuf<float, 4><<<257 * 4, 256, 0, stream>>>(xa, woT, out, Mrows);
}

// Round 14
// 164.290 us; speedup vs baseline: 1.3986x; 1.3986x over previous
//
#include <hip/hip_runtime.h>
#include <hip/hip_bf16.h>
#include <cstdint>
#include <cstddef>

using bf16 = __hip_bfloat16;
using short8 = __attribute__((ext_vector_type(8))) short;
using f32x4  = __attribute__((ext_vector_type(4))) float;

constexpr int Bc = 8;
constexpr int Tc = 4097;
constexpr int Dc = 512;         // model dim
constexpr int Hc = 8;
constexpr int Mrows = Bc * Tc;  // 32776
constexpr int Mpad2 = 33024;    // padded rows
constexpr int NW = 64;          // windows per (b,h)

__device__ __forceinline__ float bf2f(unsigned short u) {
    union { unsigned int i; float f; } v;
    v.i = ((unsigned int)u) << 16;
    return v.f;
}

__device__ __forceinline__ unsigned short f2b(float f) {
    union { float f; unsigned int i; } u; u.f = f;
    unsigned int r = u.i + 0x7FFFu + ((u.i >> 16) & 1u);  // RNE
    return (unsigned short)(r >> 16);
}

__device__ __forceinline__ void gload_lds16(const void* g, void* l) {
    __builtin_amdgcn_global_load_lds(
        (const __attribute__((address_space(1))) void*)g,
        (__attribute__((address_space(3))) void*)l, 16, 0, 0);
}

// ---------------------------------------------------------------------------
// Merged conversion kernel (one launch, partitioned by block range):
//   blocks [0, NBX)          : x fp32 [Mrows][512] -> xa bf16 [Mpad2][512]
//   blocks [NBX, NBX+768)    : w_qkv fp32 [512][1536] -> wqT bf16 [1536][512]
//   blocks [NBX+768, +256)   : w_out fp32 [512][512]  -> woT bf16 [512][512]
// ---------------------------------------------------------------------------
constexpr int NBX = (int)(((size_t)Mpad2 * 512 / 8 + 255) / 256);

__global__ __launch_bounds__(256)
void k_cvt_all(const float* __restrict__ x, const float* __restrict__ w_qkv,
               const float* __restrict__ w_out, bf16* __restrict__ xa,
               bf16* __restrict__ wqT, bf16* __restrict__ woT)
{
    int blk = blockIdx.x;
    if (blk < NBX) {
        size_t i8 = ((size_t)blk * 256 + threadIdx.x) * 8;
        if (i8 >= (size_t)Mpad2 * 512) return;
        union { short s[8]; short8 v; } o;
        if (i8 < (size_t)Mrows * 512) {
            float4 v0 = *(const float4*)(x + i8);
            float4 v1 = *(const float4*)(x + i8 + 4);
            o.s[0] = (short)f2b(v0.x); o.s[1] = (short)f2b(v0.y);
            o.s[2] = (short)f2b(v0.z); o.s[3] = (short)f2b(v0.w);
            o.s[4] = (short)f2b(v1.x); o.s[5] = (short)f2b(v1.y);
            o.s[6] = (short)f2b(v1.z); o.s[7] = (short)f2b(v1.w);
        } else {
            o.v = short8{0,0,0,0,0,0,0,0};
        }
        *(short8*)((short*)xa + i8) = o.v;
        return;
    }
    // weight transpose: 32x32 tiles via LDS
    __shared__ float t[32][33];
    const float* w; bf16* wT; int K, N, tile;
    if (blk < NBX + 768) { w = w_qkv; wT = wqT; K = 512; N = 1536; tile = blk - NBX; }
    else                 { w = w_out; wT = woT; K = 512; N = 512;  tile = blk - NBX - 768; }
    const int ntx = N / 32;
    int bn = (tile % ntx) * 32, bk = (tile / ntx) * 32;
    int tx = threadIdx.x & 31, ty = threadIdx.x >> 5;  // 32 x 8
    #pragma unroll
    for (int j = 0; j < 4; ++j)
        t[ty + j * 8][tx] = w[(size_t)(bk + ty + j * 8) * N + bn + tx];
    __syncthreads();
    #pragma unroll
    for (int j = 0; j < 4; ++j)
        wT[(size_t)(bn + ty + j * 8) * K + bk + tx] =
            __float2bfloat16(t[tx][ty + j * 8]);
}

// ---------------------------------------------------------------------------
// 128x128-tile, BK=64, 4-wave (2Mx2N) double-buffered MFMA GEMM with counted
// vmcnt pipeline. 64 KiB LDS => 2 blocks/CU.  (r6 structure, verbatim:
// measured 87us QKV / 0 bank conflicts — optimum of 7 tested structures.)
// ---------------------------------------------------------------------------
template <typename OutT, int NT>
__global__ __launch_bounds__(256)
void k_gemm_dbuf(const bf16* __restrict__ A, const bf16* __restrict__ Bt,
                 OutT* __restrict__ C, int Mlim)
{
    constexpr int N = NT * 128;
    __shared__ short lds[32768];   // 2 bufs x (A 8192 | B 8192) shorts = 64 KiB

    const int tid = threadIdx.x;
    const int lane = tid & 63, wave = tid >> 6;
    const int lo = lane & 15, g = lane >> 4;
    const int wr = wave >> 1, wc = wave & 1;

    // bijective XCD swizzle (m204), m-tile-major linear id
    const int nwg = 257 * NT;
    const int orig = blockIdx.x;
    const int qq = nwg >> 3, rr = nwg & 7;
    const int xc = orig & 7, o8 = orig >> 3;
    const int swz = (xc < rr ? xc * (qq + 1) : rr * (qq + 1) + (xc - rr) * qq) + o8;
    const int bm = (swz / NT) * 128, bn = (swz % NT) * 128;

    // ---- staging: tile = 128 rows x 8 chunks(16B); thread handles 4 A + 4 B
    const bf16* aSrc[4]; const bf16* bSrc[4];
    int dstOff[4];
    #pragma unroll
    for (int i = 0; i < 4; ++i) {
        int d = i * 256 + tid;
        int row = d >> 3, c = d & 7;
        int ck = (c - row) & 7;                 // rotated source chunk
        aSrc[i] = A  + (size_t)(bm + row) * 512 + ck * 8;
        bSrc[i] = Bt + (size_t)(bn + row) * 512 + ck * 8;
        dstOff[i] = d * 8;                      // linear LDS (shorts)
    }

    auto STAGE = [&](int kt) {
        const int bb = (kt & 1) * 16384;
        #pragma unroll
        for (int i = 0; i < 4; ++i)
            gload_lds16(aSrc[i] + kt * 64, lds + bb + dstOff[i]);
        #pragma unroll
        for (int i = 0; i < 4; ++i)
            gload_lds16(bSrc[i] + kt * 64, lds + bb + 8192 + dstOff[i]);
    };

    // ---- fragment read constants (row stride 64 shorts = 128 B) ----
    const int colk[2] = { (g + (lo & 7)) & 7, (g + 4 + (lo & 7)) & 7 };
    const int arow0 = wr * 64 + lo;
    const int brow0 = wc * 64 + lo;

    f32x4 acc[4][4] = {};

    STAGE(0);
    STAGE(1);
    asm volatile("s_waitcnt vmcnt(8)" ::: "memory");   // K-tile 0 landed
    __builtin_amdgcn_s_barrier();

    for (int t = 0; t < 8; ++t) {
        const short* bufA = lds + (t & 1) * 16384;
        const short* bufB = bufA + 8192;

        #pragma unroll
        for (int ks = 0; ks < 2; ++ks) {
            const int col = colk[ks];
            short8 af[4], bfr[4];
            #pragma unroll
            for (int mi = 0; mi < 4; ++mi)
                af[mi] = *(const short8*)(bufA + (arow0 + mi * 16) * 64 + col * 8);
            #pragma unroll
            for (int ni = 0; ni < 4; ++ni)
                bfr[ni] = *(const short8*)(bufB + (brow0 + ni * 16) * 64 + col * 8);
            __builtin_amdgcn_s_setprio(1);
            #pragma unroll
            for (int mi = 0; mi < 4; ++mi)
                #pragma unroll
                for (int ni = 0; ni < 4; ++ni)
                    acc[mi][ni] = __builtin_amdgcn_mfma_f32_16x16x32_bf16(
                        bfr[ni], af[mi], acc[mi][ni], 0, 0, 0);
            __builtin_amdgcn_s_setprio(0);
        }

        // all waves done reading buf[t&1] before its overwrite by STAGE(t+2)
        asm volatile("s_waitcnt lgkmcnt(0)" ::: "memory");
        __builtin_amdgcn_s_barrier();
        if (t < 6) {
            STAGE(t + 2);                                 // into buf[t&1]
            asm volatile("s_waitcnt vmcnt(8)" ::: "memory");  // K-tile t+1 ready
            __builtin_amdgcn_s_barrier();
        } else if (t == 6) {
            asm volatile("s_waitcnt vmcnt(0)" ::: "memory");  // K-tile 7 ready
            __builtin_amdgcn_s_barrier();
        }
    }

    // ---- epilogue: m = lane&15 dim, n = (lane>>4)*4 + r (vector stores) ----
    #pragma unroll
    for (int mi = 0; mi < 4; ++mi) {
        int m = bm + wr * 64 + mi * 16 + lo;
        if (m < Mlim) {
            #pragma unroll
            for (int ni = 0; ni < 4; ++ni) {
                int n = bn + wc * 64 + ni * 16 + g * 4;
                if constexpr (sizeof(OutT) == 2) {
                    ushort4 o = { f2b(acc[mi][ni][0]), f2b(acc[mi][ni][1]),
                                  f2b(acc[mi][ni][2]), f2b(acc[mi][ni][3]) };
                    *(ushort4*)((bf16*)C + (size_t)m * N + n) = o;
                } else {
                    float4 o = { acc[mi][ni][0], acc[mi][ni][1],
                                 acc[mi][ni][2], acc[mi][ni][3] };
                    *(float4*)((float*)C + (size_t)m * N + n) = o;
                }
            }
        }
    }
}

// ---------------------------------------------------------------------------
// Window attention (tokens 1..4096), MFMA, with fused token-0 partials.
// (r9 version, unchanged)
// ---------------------------------------------------------------------------
__global__ __launch_bounds__(256)
void k_attn_win(const bf16* __restrict__ qkv, bf16* __restrict__ aout,
                float* __restrict__ part)
{
    __shared__ __attribute__((aligned(16))) unsigned short pS[64 * 64];
    __shared__ __attribute__((aligned(16))) unsigned short vT[64 * 64];
    __shared__ float q0s[64];
    __shared__ float pTok[64];
    __shared__ float oPart[4][64];

    const int n = blockIdx.x, h = blockIdx.y, b = blockIdx.z;
    const int tid = threadIdx.x;
    const int wave = tid >> 6, lane = tid & 63;
    const int lo = lane & 15, g = lane >> 4;

    const bf16* base = qkv + ((size_t)b * Tc + 1 + (size_t)n * 64) * 1536 + h * 64;
    const bf16* kbase = base + 512;
    const bf16* vbase = base + 1024;

    {
        const int key = tid & 63;
        const int d0 = (tid >> 6) * 16;
        const bf16* vp = vbase + (size_t)key * 1536 + d0;
        ushort4 u[4];
        #pragma unroll
        for (int q = 0; q < 4; ++q) u[q] = *(const ushort4*)(vp + q * 4);
        const unsigned short vals[16] = {
            u[0].x, u[0].y, u[0].z, u[0].w, u[1].x, u[1].y, u[1].z, u[1].w,
            u[2].x, u[2].y, u[2].z, u[2].w, u[3].x, u[3].y, u[3].z, u[3].w };
        #pragma unroll
        for (int j = 0; j < 16; ++j) {
            int d = d0 + j;
            int byteoff = d * 128 + ((key * 2) ^ ((d & 7) << 4));
            *(unsigned short*)((char*)vT + byteoff) = vals[j];
        }
    }

    if (tid < 64)
        q0s[tid] = bf2f(*(const unsigned short*)
            (qkv + (size_t)b * Tc * 1536 + h * 64 + tid));

    short8 qf[2];
    {
        const bf16* qp = base + (size_t)(wave * 16 + lo) * 1536 + g * 8;
        qf[0] = *(const short8*)(qp);
        qf[1] = *(const short8*)(qp + 32);
    }

    f32x4 sacc[4] = {};
    #pragma unroll
    for (int ni = 0; ni < 4; ++ni) {
        const bf16* kp = kbase + (size_t)(ni * 16 + lo) * 1536 + g * 8;
        short8 k0 = *(const short8*)(kp);
        short8 k1 = *(const short8*)(kp + 32);
        sacc[ni] = __builtin_amdgcn_mfma_f32_16x16x32_bf16(qf[0], k0, sacc[ni], 0, 0, 0);
        sacc[ni] = __builtin_amdgcn_mfma_f32_16x16x32_bf16(qf[1], k1, sacc[ni], 0, 0, 0);
    }

    __syncthreads();  // barrier 1: vT + q0s ready

    float m_w = 0.f, s_w = 0.f;
    if (wave == 0) {
        const bf16* kp = kbase + (size_t)lane * 1536;
        float l = 0.f;
        #pragma unroll
        for (int d8 = 0; d8 < 8; ++d8) {
            short8 kv = *(const short8*)(kp + d8 * 8);
            #pragma unroll
            for (int e = 0; e < 8; ++e)
                l = fmaf(q0s[d8 * 8 + e], bf2f((unsigned short)kv[e]), l);
        }
        l *= 0.125f;
        float mm = l;
        #pragma unroll
        for (int off = 1; off < 64; off <<= 1) mm = fmaxf(mm, __shfl_xor(mm, off));
        float p = __expf(l - mm);
        float ss = p;
        #pragma unroll
        for (int off = 1; off < 64; off <<= 1) ss += __shfl_xor(ss, off);
        pTok[lane] = p;
        m_w = mm; s_w = ss;
    }

    float pv[4][4];
    float inv[4];
    #pragma unroll
    for (int r = 0; r < 4; ++r) {
        float m = fmaxf(fmaxf(sacc[0][r], sacc[1][r]),
                        fmaxf(sacc[2][r], sacc[3][r])) * 0.125f;
        m = fmaxf(m, __shfl_xor(m, 1));
        m = fmaxf(m, __shfl_xor(m, 2));
        m = fmaxf(m, __shfl_xor(m, 4));
        m = fmaxf(m, __shfl_xor(m, 8));
        float s = 0.f;
        #pragma unroll
        for (int ni = 0; ni < 4; ++ni) {
            float e = __expf(sacc[ni][r] * 0.125f - m);
            pv[ni][r] = e;
            s += e;
        }
        s += __shfl_xor(s, 1);
        s += __shfl_xor(s, 2);
        s += __shfl_xor(s, 4);
        s += __shfl_xor(s, 8);
        inv[r] = 1.f / s;
    }

    #pragma unroll
    for (int ni = 0; ni < 4; ++ni) {
        #pragma unroll
        for (int r = 0; r < 4; ++r) {
            int qrow = wave * 16 + g * 4 + r;
            int col = ni * 16 + lo;
            int byteoff = qrow * 128 + ((col * 2) ^ ((qrow & 7) << 4));
            *(unsigned short*)((char*)pS + byteoff) = f2b(pv[ni][r]);
        }
    }
    __syncthreads();  // barrier 2: pS + pTok ready

    f32x4 oacc[4] = {};
    #pragma unroll
    for (int s = 0; s < 2; ++s) {
        int arow2 = wave * 16 + lo;
        int abyte = arow2 * 128 + (((s * 32 + g * 8) * 2) ^ ((arow2 & 7) << 4));
        short8 pa = *(const short8*)((const char*)pS + abyte);
        #pragma unroll
        for (int nd = 0; nd < 4; ++nd) {
            int d = nd * 16 + lo;
            int bbyte = d * 128 + (((s * 32 + g * 8) * 2) ^ ((d & 7) << 4));
            short8 vb = *(const short8*)((const char*)vT + bbyte);
            oacc[nd] = __builtin_amdgcn_mfma_f32_16x16x32_bf16(pa, vb, oacc[nd], 0, 0, 0);
        }
    }

    {
        const int d = tid & 63, qq = tid >> 6;
        float po = 0.f;
        #pragma unroll
        for (int j16 = 0; j16 < 16; ++j16) {
            int j = qq * 16 + j16;
            int byteoff = d * 128 + ((j * 2) ^ ((d & 7) << 4));
            po = fmaf(pTok[j],
                      bf2f(*(const unsigned short*)((const char*)vT + byteoff)),
                      po);
        }
        oPart[qq][d] = po;
    }

    #pragma unroll
    for (int nd = 0; nd < 4; ++nd) {
        #pragma unroll
        for (int r = 0; r < 4; ++r) {
            int t = 1 + n * 64 + wave * 16 + g * 4 + r;
            aout[((size_t)b * Tc + t) * Dc + h * 64 + nd * 16 + lo] =
                __float2bfloat16(oacc[nd][r] * inv[r]);
        }
    }

    __syncthreads();  // barrier 3: oPart ready

    if (tid < 64) {
        float o0 = oPart[0][tid] + oPart[1][tid] + oPart[2][tid] + oPart[3][tid];
        float* pout = part + ((size_t)(b * Hc + h) * NW + n) * 66;
        pout[tid] = o0;
        if (tid == 0) { pout[64] = m_w; pout[65] = s_w; }
    }
}

// ---------------------------------------------------------------------------
// Token-0 reduce: combine 64 window partials + the key-0 term per (b,h).
// (r9 version, unchanged)
// ---------------------------------------------------------------------------
__global__ __launch_bounds__(64)
void k_tok0_reduce(const float* __restrict__ part, const bf16* __restrict__ qkv,
                   bf16* __restrict__ aout)
{
    const int h = blockIdx.x, b = blockIdx.y;
    const int lane = threadIdx.x;
    const float* basep = part + (size_t)(b * Hc + h) * NW * 66;
    const bf16* qrow = qkv + (size_t)b * Tc * 1536 + h * 64;

    float l0 = bf2f(*(const unsigned short*)(qrow + lane)) *
               bf2f(*(const unsigned short*)(qrow + 512 + lane));
    #pragma unroll
    for (int off = 1; off < 64; off <<= 1) l0 += __shfl_xor(l0, off);
    l0 *= 0.125f;

    float M = basep[lane * 66 + 64];
    #pragma unroll
    for (int off = 1; off < 64; off <<= 1) M = fmaxf(M, __shfl_xor(M, off));
    M = fmaxf(M, l0);

    float S = 0.f, o = 0.f;
    for (int c = 0; c < NW; ++c) {
        const float* pp = basep + c * 66;
        float w = __expf(pp[64] - M);
        S += pp[65] * w;
        o = fmaf(pp[lane], w, o);
    }
    float p0 = __expf(l0 - M);
    S += p0;
    o = fmaf(p0, bf2f(*(const unsigned short*)(qrow + 1024 + lane)), o);

    aout[(size_t)b * Tc * Dc + h * 64 + lane] = __float2bfloat16(o / S);
}

// ---------------------------------------------------------------------------
extern "C" void kernel_launch(void* const* d_in, const int* in_sizes, int n_in,
                              void* d_out, int out_size, void* d_ws, size_t ws_size,
                              hipStream_t stream)
{
    const float* x     = (const float*)d_in[0];
    const float* w_qkv = (const float*)d_in[1];
    const float* w_out = (const float*)d_in[2];
    float* out = (float*)d_out;

    // ws layout (bf16 elems): qkv [Mrows*1536] | xa [Mpad2*512] (xb & aout
    // share; rows >= Mrows stay zero from cvt pad) | wqT [1536*512] |
    // woT [512*512]. token-0 partials reuse wqT (dead after QKV GEMM).
    bf16* qkv = (bf16*)d_ws;
    bf16* xa  = qkv + (size_t)Mrows * 1536;
    bf16* wqT = xa  + (size_t)Mpad2 * 512;
    bf16* woT = wqT + (size_t)1536 * 512;
    float* part = (float*)wqT;

    // 1) all conversions in one launch (x -> xa, w_qkv -> wqT, w_out -> woT)
    k_cvt_all<<<NBX + 768 + 256, 256, 0, stream>>>(x, w_qkv, w_out, xa, wqT, woT);

    // 2) qkv = x @ w_qkv  (r6 dbuf — measured optimum of 7 structures)
    k_gemm_dbuf<bf16, 12><<<257 * 12, 256, 0, stream>>>(xa, wqT, qkv, Mrows);

    // 3) attention: MFMA windows with fused token-0 partials, then reduce
    k_attn_win<<<dim3(64, Hc, Bc), 256, 0, stream>>>(qkv, xa, part);
    k_tok0_reduce<<<dim3(Hc, Bc), dim3(64), 0, stream>>>(part, qkv, xa);

    // 4) out = attn_out @ w_out  (r6 dbuf — near memory floor)
    k_gemm_dbuf<float, 4><<<257 * 4, 256, 0, stream>>>(xa, woT, out, Mrows);
}